// Round 4
// baseline (522.685 us; speedup 1.0000x reference)
//
#include <hip/hip_runtime.h>
#include <hip/hip_bf16.h>
#include <hip/hip_fp16.h>
#include <cmath>

#define BB   8
#define CIN  8
#define TT   12
#define HH   128
#define WW   128
#define HID  32
#define CCOMB 40
#define HW   (HH * WW)

// LDS layout (u16 units): tile1 [240][40] @0 ; tile2(rh) [180][36] @9600 ;
// tileU(fp16 u) [128][33] @16080 ; total 20304 u16 = 40,608 B -> 4 blocks/CU
#define OFF2 9600
#define OFFU 16080
#define SMEM_U16 20304

typedef __attribute__((ext_vector_type(8))) short sv8;
typedef __attribute__((ext_vector_type(4))) short sv4;
typedef __attribute__((ext_vector_type(4))) float f32x4;
typedef unsigned short u16;

__device__ inline u16 f2bf(float f) {
    union { float f; unsigned u; } v; v.f = f;
    unsigned u = v.u;
    return (u16)((u + 0x7FFFu + ((u >> 16) & 1u)) >> 16);
}
__device__ inline float bf2f(u16 h) {
    union { unsigned u; float f; } v; v.u = ((unsigned)h) << 16; return v.f;
}
__device__ inline float sigmoid_fast(float x) {
    return 1.f / (1.f + __expf(-x));
}
__device__ inline float tanh_fast(float z) {
    float a = fabsf(z);
    float r = 1.f - 2.f / (__expf(2.f * a) + 1.f);
    return copysignf(r, z);
}

// ---------------------------------------------------------------------------
// Weight fragment gather (OIHW fp32 -> bf16 A-fragment), K=(ky*40+ci), pad 120->128
// ---------------------------------------------------------------------------
__device__ inline sv8 gather_wfrag(const float* __restrict__ W,
                                   int co, int g, int kx, int ks) {
    int k0 = ks * 32 + g * 8;
    sv8 f;
    if (k0 < 120) {
        int ky  = k0 / 40;
        int ci0 = k0 - ky * 40;
#pragma unroll
        for (int i = 0; i < 8; ++i)
            f[i] = (short)f2bf(W[(((size_t)co * CCOMB + ci0 + i) * 3 + ky) * 3 + kx]);
    } else {
#pragma unroll
        for (int i = 0; i < 8; ++i) f[i] = 0;
    }
    return f;
}

// pack layout: [Gall(6 = 4 gates + 2 cand)][f(12)][lane(64)][8 bf16]
__global__ void pack_weights(const float* __restrict__ Wg,
                             const float* __restrict__ Wc,
                             u16* __restrict__ pack) {
    int tid = blockIdx.x * blockDim.x + threadIdx.x;
    if (tid >= 6 * 12 * 64) return;
    int lane = tid & 63;
    int f    = (tid >> 6) % 12;
    int Gall = tid / (12 * 64);
    int kx = f >> 2, ks = f & 3;
    int g = lane >> 4;
    sv8 v;
    if (Gall < 4) v = gather_wfrag(Wg, Gall * 16 + (lane & 15), g, kx, ks);
    else          v = gather_wfrag(Wc, (Gall - 4) * 16 + (lane & 15), g, kx, ks);
    *(sv8*)&pack[(size_t)tid * 8] = v;
}

// x (B,CIN,T,H,W) fp32 -> xbf (B,T,HW,8) bf16
__global__ __launch_bounds__(256) void x_to_bf16(const float* __restrict__ x,
                                                 u16* __restrict__ xbf) {
    int gid = blockIdx.x * 256 + threadIdx.x;
    if (gid >= BB * TT * HW) return;
    int p  = gid & (HW - 1);
    int bt = gid >> 14;
    int t = bt % TT, b = bt / TT;
    sv8 v;
#pragma unroll
    for (int c = 0; c < 8; ++c)
        v[c] = (short)f2bf(x[(((size_t)b * CIN + c) * TT + t) * HW + p]);
    *(sv8*)&xbf[(size_t)gid * 8] = v;
}

// ---------------------------------------------------------------------------
// Fused GRU step. Block = 256 thr (4 waves), output tile 16 cols x 8 rows.
// Phase 1: gates conv (40->64) on 18x10 halo region; rh -> tile2, u -> tileU.
// Phase 2: cand conv (40->32) on inner 16x8; tanh + blend; write out/hbf.
// Grid (8, 16, 8) = 1024 blocks = exactly 4 blocks/CU.
// ---------------------------------------------------------------------------
__global__ __launch_bounds__(256, 4) void gru_step(
    const u16* __restrict__ xbf, const u16* __restrict__ wpack,
    const float* __restrict__ bg, const float* __restrict__ bc,
    u16* __restrict__ hbf, float* __restrict__ out,
    float* __restrict__ hlast, int t)
{
    __shared__ __align__(16) u16 smem[SMEM_U16];
    const int b  = blockIdx.z;
    const int x0 = blockIdx.x * 16, y0 = blockIdx.y * 8;
    const int tid = threadIdx.x, lane = tid & 63, w = tid >> 6;
    const int m = lane & 15, g = lane >> 4;

    // ---- stage tile1: 12 rows x 20 cols, ch 0..8 = x, 8..40 = h ----
    const u16* hb = hbf + (size_t)b * HW * 32;
    for (int idx = tid; idx < 960; idx += 256) {
        int pix = idx >> 2, q = idx & 3;
        int r = pix / 20, c = pix - r * 20;
        int gy = y0 + r - 2, gx = x0 + c - 2;
        sv8 v = {};
        if ((unsigned)gy < 128u && (unsigned)gx < 128u)
            v = *(const sv8*)&hb[(size_t)(gy * WW + gx) * 32 + q * 8];
        *(sv8*)&smem[pix * 40 + 8 + q * 8] = v;
    }
    const u16* xb = xbf + ((size_t)b * TT + t) * HW * 8;
    for (int idx = tid; idx < 240; idx += 256) {
        int r = idx / 20, c = idx - r * 20;
        int gy = y0 + r - 2, gx = x0 + c - 2;
        sv8 v = {};
        if ((unsigned)gy < 128u && (unsigned)gx < 128u)
            v = *(const sv8*)&xb[(size_t)(gy * WW + gx) * 8];
        *(sv8*)&smem[idx * 40] = v;
    }

    // per-lane (ky, ci0) per k-step
    int kyv[4], ci0v[4];
#pragma unroll
    for (int ks = 0; ks < 4; ++ks) {
        int k0 = ks * 32 + g * 8;
        kyv[ks] = 0; ci0v[ks] = 0;
        if (k0 < 120) { kyv[ks] = k0 / 40; ci0v[ks] = k0 - kyv[ks] * 40; }
    }

    // gates weights: wave w <-> co-group w
    sv8 wf[12];
#pragma unroll
    for (int f = 0; f < 12; ++f)
        wf[f] = *(const sv8*)&wpack[(((size_t)w * 12 + f) * 64 + lane) * 8];
    const int co0g = w * 16 + g * 4;
    float bias[4];
#pragma unroll
    for (int r = 0; r < 4; ++r) bias[r] = bg[co0g + r];

    __syncthreads();

    // ---- phase 1: gates over 18x10 region (180 px, 12 groups of 16) ----
    const bool isReset = (w < 2);
    for (int j = 0; j < 12; ++j) {
        int p2 = j * 16 + m;
        bool valid = p2 < 180;
        int px = valid ? p2 : 179;
        int yy = px / 18, xx = px - yy * 18;
        f32x4 acc = {0.f, 0.f, 0.f, 0.f};
#pragma unroll
        for (int kx = 0; kx < 3; ++kx)
#pragma unroll
            for (int ks = 0; ks < 4; ++ks) {
                sv8 bv = *(const sv8*)&smem[((yy + kyv[ks]) * 20 + xx + kx) * 40 + ci0v[ks]];
                acc = __builtin_amdgcn_mfma_f32_16x16x32_bf16(wf[kx * 4 + ks], bv, acc, 0, 0, 0);
            }
        if (isReset) {
            // rh = sigmoid(.) * h ; staged h is 0 outside image -> rh auto-0
            sv4 h4 = *(const sv4*)&smem[((yy + 1) * 20 + xx + 1) * 40 + 8 + co0g];
            sv4 rh4;
#pragma unroll
            for (int r = 0; r < 4; ++r) {
                float gv = sigmoid_fast(acc[r] + bias[r]);
                rh4[r] = (short)f2bf(gv * bf2f((u16)h4[r]));
            }
            if (valid) *(sv4*)&smem[OFF2 + px * 36 + co0g] = rh4;
        } else {
            int u0 = co0g - 32;
            u16 uv[4];
#pragma unroll
            for (int r = 0; r < 4; ++r)
                uv[r] = __half_as_ushort(__float2half(sigmoid_fast(acc[r] + bias[r])));
            if (valid && yy >= 1 && yy <= 8 && xx >= 1 && xx <= 16) {
                int ub = OFFU + ((yy - 1) * 16 + (xx - 1)) * 33 + u0;
                smem[ub]     = uv[0];
                smem[ub + 1] = uv[1];
                smem[ub + 2] = uv[2];
                smem[ub + 3] = uv[3];
            }
        }
    }

    // cand weights: wave w -> co-group (w&1), rows (w>>1)*4 ..+3
    const int cg = w & 1;
    sv8 wc[12];
#pragma unroll
    for (int f = 0; f < 12; ++f)
        wc[f] = *(const sv8*)&wpack[(((size_t)(4 + cg) * 12 + f) * 64 + lane) * 8];
    const int co0c = cg * 16 + g * 4;
    float biasc[4];
#pragma unroll
    for (int r = 0; r < 4; ++r) biasc[r] = bc[co0c + r];

    __syncthreads();

    // ---- phase 2: cand conv + blend over inner 16x8 ----
    const int rbase = (w >> 1) * 4;
#pragma unroll
    for (int k = 0; k < 4; ++k) {
        int jj = rbase + k;
        f32x4 acc = {0.f, 0.f, 0.f, 0.f};
#pragma unroll
        for (int kx = 0; kx < 3; ++kx)
#pragma unroll
            for (int ks = 0; ks < 4; ++ks) {
                // x-runs (ci0==0) come from tile1; rh-runs from tile2
                int a_x  = ((jj + kyv[ks] + 1) * 20 + (m + kx + 1)) * 40;
                int a_rh = OFF2 + ((jj + kyv[ks]) * 18 + (m + kx)) * 36 + (ci0v[ks] - 8);
                int addr = (ci0v[ks] == 0) ? a_x : a_rh;
                sv4 lo = *(const sv4*)&smem[addr];
                sv4 hi = *(const sv4*)&smem[addr + 4];
                sv8 bv = __builtin_shufflevector(lo, hi, 0, 1, 2, 3, 4, 5, 6, 7);
                acc = __builtin_amdgcn_mfma_f32_16x16x32_bf16(wc[kx * 4 + ks], bv, acc, 0, 0, 0);
            }
        int yo = y0 + jj, xo = x0 + m;
        int ub = OFFU + (jj * 16 + m) * 33 + co0c;
        sv4 h4 = *(const sv4*)&smem[((jj + 2) * 20 + m + 2) * 40 + 8 + co0c];
        sv4 hn4;
#pragma unroll
        for (int r = 0; r < 4; ++r) {
            float cv   = tanh_fast(acc[r] + biasc[r]);
            float u    = __half2float(__ushort_as_half(smem[ub + r]));
            float hold = bf2f((u16)h4[r]);
            float hn = (1.f - u) * hold + u * cv;
            out[(((size_t)b * HID + co0c + r) * TT + t) * HW + yo * WW + xo] = hn;
            hn4[r] = (short)f2bf(hn);
            if (t == TT - 1)
                hlast[((size_t)b * HID + co0c + r) * HW + yo * WW + xo] = hn;
        }
        *(sv4*)&hbf[((size_t)b * HW + yo * WW + xo) * 32 + co0c] = hn4;
    }
}

extern "C" void kernel_launch(void* const* d_in, const int* in_sizes, int n_in,
                              void* d_out, int out_size, void* d_ws, size_t ws_size,
                              hipStream_t stream) {
    const float* x  = (const float*)d_in[0];
    const float* Wg = (const float*)d_in[1];
    const float* bg = (const float*)d_in[2];
    const float* Wc = (const float*)d_in[3];
    const float* bc = (const float*)d_in[4];

    float* out   = (float*)d_out;
    float* hlast = out + (size_t)BB * HID * TT * HW;

    const size_t PLANE = (size_t)BB * HW * 32 * sizeof(u16);     // 8.39 MB
    const size_t PACKB = (size_t)6 * 12 * 64 * 8 * sizeof(u16);  // 73.7 KB
    char* ws = (char*)d_ws;
    u16* hbf   = (u16*)ws;
    u16* wpack = (u16*)(ws + PLANE);
    u16* xbf   = (u16*)(ws + PLANE + PACKB);

    pack_weights<<<(6 * 12 * 64 + 255) / 256, 256, 0, stream>>>(Wg, Wc, wpack);
    x_to_bf16<<<(BB * TT * HW) / 256, 256, 0, stream>>>(x, xbf);
    hipMemsetAsync(hbf, 0, PLANE, stream);

    for (int t = 0; t < TT; ++t) {
        gru_step<<<dim3(WW / 16, HH / 8, BB), 256, 0, stream>>>(
            xbf, wpack, bg, bc, hbf, out, hlast, t);
    }
}